// Round 1
// baseline (26.359 us; speedup 1.0000x reference)
//
#include <hip/hip_runtime.h>
#include <math.h>

#define VOCAB 100000
#define DIM   128
#define BATCH 16384
#define NEG   10

// Numerically stable log-sigmoid: log(1/(1+e^-x)) = min(x,0) - log1p(e^-|x|)
__device__ __forceinline__ float logsig(float x) {
    float ax = fabsf(x);
    float l  = log1pf(expf(-ax));
    return (x >= 0.0f) ? -l : (x - l);
}

// Stage 1: one 64-lane wave per batch row; 4 waves (256 threads) per block.
// Each block writes one partial loss to d_ws.
__global__ __launch_bounds__(256) void sg_partial_kernel(
    const float* __restrict__ focus_W,
    const float* __restrict__ context_W,
    const int*   __restrict__ focus_idx,
    const int*   __restrict__ context_idx,
    const int*   __restrict__ neg_idx,
    float*       __restrict__ partial)
{
    const int wave = threadIdx.x >> 6;          // 0..3
    const int lane = threadIdx.x & 63;          // 0..63
    const int row  = blockIdx.x * 4 + wave;     // batch row

    float contrib = 0.0f;
    if (row < BATCH) {
        const int fi = focus_idx[row];
        const int ci = context_idx[row];

        // lane i holds elements [2i, 2i+1] of the 128-dim embedding
        const float2 f = *(const float2*)(focus_W   + (size_t)fi * DIM + lane * 2);
        const float2 c = *(const float2*)(context_W + (size_t)ci * DIM + lane * 2);

        // Sum the 10 negative context rows first (einsum result is summed over K,
        // so neg_score = dot(focus, sum_k context_W[nk]))
        float2 nsum = make_float2(0.0f, 0.0f);
        #pragma unroll
        for (int k = 0; k < NEG; ++k) {
            const int ni = neg_idx[(size_t)row * NEG + k];
            const float2 n = *(const float2*)(context_W + (size_t)ni * DIM + lane * 2);
            nsum.x += n.x;
            nsum.y += n.y;
        }

        float pos = f.x * c.x    + f.y * c.y;
        float neg = f.x * nsum.x + f.y * nsum.y;

        // 64-lane butterfly reduction (wave = 64 on CDNA!)
        #pragma unroll
        for (int off = 32; off > 0; off >>= 1) {
            pos += __shfl_xor(pos, off);
            neg += __shfl_xor(neg, off);
        }

        if (lane == 0) {
            float pp = logsig(pos);
            float np = logsig(neg);
            contrib = (1.0f - pp) * (1.0f - pp) + np * np;
        }
    }

    __shared__ float s[4];
    if (lane == 0) s[wave] = contrib;
    __syncthreads();
    if (threadIdx.x == 0) {
        partial[blockIdx.x] = (s[0] + s[1]) + (s[2] + s[3]);
    }
}

// Stage 2: single block reduces the per-block partials -> d_out[0].
// Deterministic (no atomics), and overwrites d_out so no zero-init needed.
__global__ __launch_bounds__(256) void sg_final_kernel(
    const float* __restrict__ partial, int n, float* __restrict__ out)
{
    float s = 0.0f;
    for (int i = threadIdx.x; i < n; i += 256) s += partial[i];

    #pragma unroll
    for (int off = 32; off > 0; off >>= 1) s += __shfl_xor(s, off);

    __shared__ float ws[4];
    const int wave = threadIdx.x >> 6;
    const int lane = threadIdx.x & 63;
    if (lane == 0) ws[wave] = s;
    __syncthreads();
    if (threadIdx.x == 0) out[0] = (ws[0] + ws[1]) + (ws[2] + ws[3]);
}

extern "C" void kernel_launch(void* const* d_in, const int* in_sizes, int n_in,
                              void* d_out, int out_size, void* d_ws, size_t ws_size,
                              hipStream_t stream) {
    const float* focus_W     = (const float*)d_in[0];
    const float* context_W   = (const float*)d_in[1];
    const int*   focus_idx   = (const int*)d_in[2];
    const int*   context_idx = (const int*)d_in[3];
    const int*   neg_idx     = (const int*)d_in[4];
    float*       out         = (float*)d_out;
    float*       partial     = (float*)d_ws;   // 4096 floats = 16 KB scratch

    const int blocks = (BATCH + 3) / 4;        // 4096 blocks, 1 wave per row

    sg_partial_kernel<<<blocks, 256, 0, stream>>>(
        focus_W, context_W, focus_idx, context_idx, neg_idx, partial);
    sg_final_kernel<<<1, 256, 0, stream>>>(partial, blocks, out);
}

// Round 2
// 24.146 us; speedup vs baseline: 1.0916x; 1.0916x over previous
//
#include <hip/hip_runtime.h>
#include <math.h>

#define VOCAB 100000
#define DIM   128
#define BATCH 16384
#define NEG   10

// Numerically stable log-sigmoid: log(1/(1+e^-x)) = min(x,0) - log1p(e^-|x|)
__device__ __forceinline__ float logsig(float x) {
    float ax = fabsf(x);
    float l  = log1pf(expf(-ax));
    return (x >= 0.0f) ? -l : (x - l);
}

// Stage 1: 32 lanes per batch row (float4/lane = 16B), 2 rows per wave,
// 8 rows per 256-thread block. Grid = BATCH/8 = 2048 blocks = 8192 waves
// = exactly 32 waves/CU on 256 CUs (one fully-resident occupancy batch).
__global__ __launch_bounds__(256) void sg_partial_kernel(
    const float* __restrict__ focus_W,
    const float* __restrict__ context_W,
    const int*   __restrict__ focus_idx,
    const int*   __restrict__ context_idx,
    const int*   __restrict__ neg_idx,
    float*       __restrict__ partial)
{
    const int t    = threadIdx.x;
    const int sub  = t >> 5;                 // 0..7: which row-slot in block
    const int lane = t & 31;                 // lane within the 32-lane row group
    const int row  = blockIdx.x * 8 + sub;   // batch row (BATCH % 8 == 0)

    const int fi = focus_idx[row];
    const int ci = context_idx[row];

    // lane holds elements [4*lane .. 4*lane+3] of the 128-dim embedding
    const float4 f = *(const float4*)(focus_W   + (size_t)fi * DIM + lane * 4);
    const float4 c = *(const float4*)(context_W + (size_t)ci * DIM + lane * 4);

    // einsum over K then sum -> neg_score = dot(focus, sum_k context_W[nk]);
    // sum the 10 negative rows first (independent gathers, all in flight).
    float4 ns = make_float4(0.f, 0.f, 0.f, 0.f);
    #pragma unroll
    for (int k = 0; k < NEG; ++k) {
        const int ni = neg_idx[(size_t)row * NEG + k];
        const float4 n = *(const float4*)(context_W + (size_t)ni * DIM + lane * 4);
        ns.x += n.x; ns.y += n.y; ns.z += n.z; ns.w += n.w;
    }

    float pos = f.x * c.x  + f.y * c.y  + f.z * c.z  + f.w * c.w;
    float neg = f.x * ns.x + f.y * ns.y + f.z * ns.z + f.w * ns.w;

    // 32-lane butterfly (xor offsets < 32 stay inside each half-wave)
    #pragma unroll
    for (int off = 16; off > 0; off >>= 1) {
        pos += __shfl_xor(pos, off);
        neg += __shfl_xor(neg, off);
    }

    __shared__ float s[8];
    if (lane == 0) {
        float pp = logsig(pos);
        float np = logsig(neg);
        s[sub] = (1.0f - pp) * (1.0f - pp) + np * np;
    }
    __syncthreads();
    if (t == 0) {
        float acc = 0.f;
        #pragma unroll
        for (int i = 0; i < 8; ++i) acc += s[i];
        partial[blockIdx.x] = acc;
    }
}

// Stage 2: single block reduces the per-block partials -> d_out[0].
// Deterministic (no atomics), and overwrites d_out so no zero-init needed.
__global__ __launch_bounds__(256) void sg_final_kernel(
    const float* __restrict__ partial, int n, float* __restrict__ out)
{
    float s = 0.0f;
    for (int i = threadIdx.x; i < n; i += 256) s += partial[i];

    #pragma unroll
    for (int off = 32; off > 0; off >>= 1) s += __shfl_xor(s, off);

    __shared__ float ws[4];
    const int wave = threadIdx.x >> 6;
    const int lane = threadIdx.x & 63;
    if (lane == 0) ws[wave] = s;
    __syncthreads();
    if (threadIdx.x == 0) out[0] = (ws[0] + ws[1]) + (ws[2] + ws[3]);
}

extern "C" void kernel_launch(void* const* d_in, const int* in_sizes, int n_in,
                              void* d_out, int out_size, void* d_ws, size_t ws_size,
                              hipStream_t stream) {
    const float* focus_W     = (const float*)d_in[0];
    const float* context_W   = (const float*)d_in[1];
    const int*   focus_idx   = (const int*)d_in[2];
    const int*   context_idx = (const int*)d_in[3];
    const int*   neg_idx     = (const int*)d_in[4];
    float*       out         = (float*)d_out;
    float*       partial     = (float*)d_ws;   // 2048 floats = 8 KB scratch

    const int blocks = BATCH / 8;              // 2048 blocks, 2 rows per wave

    sg_partial_kernel<<<blocks, 256, 0, stream>>>(
        focus_W, context_W, focus_idx, context_idx, neg_idx, partial);
    sg_final_kernel<<<1, 256, 0, stream>>>(partial, blocks, out);
}